// Round 4
// baseline (570.903 us; speedup 1.0000x reference)
//
#include <hip/hip_runtime.h>

typedef __bf16 bf16x4 __attribute__((ext_vector_type(4)));
typedef __bf16 bf16x8 __attribute__((ext_vector_type(8)));
typedef float  f32x4  __attribute__((ext_vector_type(4)));

#define HWSZ 4096
#define CCH  256
#define LOG2E 1.44269504088896340736f

enum { M_SSTAT = 0, M_CONV = 1, M_G1 = 4, M_FUSE = 5 };

__device__ __forceinline__ float exp2_fast(float x) {
#if __has_builtin(__builtin_amdgcn_exp2f)
  return __builtin_amdgcn_exp2f(x);
#else
  return exp2f(x);
#endif
}

// stage 16B per lane into LDS; lane's data lands at lds_base + lane*16B
__device__ __forceinline__ void stage16(const __bf16* g, __bf16* ldsBase) {
#if __has_builtin(__builtin_amdgcn_global_load_lds)
  __builtin_amdgcn_global_load_lds(
      (const __attribute__((address_space(1))) void*)g,
      (__attribute__((address_space(3))) void*)ldsBase, 16, 0, 0);
#else
  int lane = threadIdx.x & 63;
  *(bf16x8*)(ldsBase + lane * 8) = *(const bf16x8*)g;
#endif
}

// ---------------------------------------------------------------------------
// Generic 128x128x32 bf16 MFMA GEMM, C = A * B^T, A[M,K], B[N,K] K-contiguous.
// 256 threads = 4 waves 2x2, wave 64x64 (4x4 16x16x32 MFMA tiles).
// M_CONV : merged conv3x3 GEMM. by<8: A=AL (M=1024, from Fl imgs), else A=A2=AV
//          (M=512, from Fv imgs). Outputs Q/K-type [p,c] or V-type [c,p].
// M_SSTAT: no C store; per-(128-row-chunk, column) softmax stats pm/pl only.
// M_G1   : 1x1 conv + bias + residual; blockIdx.z = br*2+z; writes concat ZZ.
// M_FUSE : 1x1 conv over 512ch + bias -> fp32 out.
// ---------------------------------------------------------------------------
template<int MODE>
__global__ __launch_bounds__(256)
void gemm_bt(const __bf16* __restrict__ A, long sAz,
             const __bf16* __restrict__ B, long sBz,
             int N, int K,
             __bf16* __restrict__ o0, __bf16* __restrict__ o1,
             __bf16* __restrict__ o2, __bf16* __restrict__ o3,
             long sOz,
             float* __restrict__ fout, long sFz,
             const float* __restrict__ bb0, const float* __restrict__ bb1,
             const float* __restrict__ bb2, const float* __restrict__ bb3,
             const float* __restrict__ resid, long sRz,
             float* __restrict__ pmo, float* __restrict__ plo,
             __bf16* __restrict__ o4, __bf16* __restrict__ o5,
             const float* __restrict__ bb4, const float* __restrict__ bb5,
             const __bf16* __restrict__ A2)
{
  __shared__ __align__(16) __bf16 smem[8192];
  __bf16* As = smem;
  __bf16* Bs = smem + 4096;

  const int tid  = threadIdx.x;
  const int lane = tid & 63;
  const int w    = tid >> 6;
  const int wm   = (w >> 1) * 64;
  const int wn   = (w & 1) * 64;
  const int z    = blockIdx.z;
  const int by   = blockIdx.y;
  const int bn   = blockIdx.x * 128;

  int bmEff = by * 128;
  const __bf16* Ab;
  const __bf16* Bb;
  if constexpr (MODE == M_CONV) {
    bool isL = (by < 8);
    bmEff = (isL ? by : by - 8) * 128;
    Ab = isL ? A : A2;
    Bb = B + (long)((isL ? 0 : 2) + z) * sBz;
  } else {
    Ab = A + (long)z * sAz;
    Bb = B + (long)z * sBz;
  }

  f32x4 acc[4][4] = {};

  const int srow = lane >> 2;       // row within 16-row staging chunk
  const int skc  = (lane & 3) * 8;  // k-element offset within row

  for (int k0 = 0; k0 < K; k0 += 32) {
#pragma unroll
    for (int j = 0; j < 2; ++j) {
      int rbase = w * 32 + j * 16;
      stage16(Ab + (long)(bmEff + rbase + srow) * K + k0 + skc, As + rbase * 32);
    }
#pragma unroll
    for (int j = 0; j < 2; ++j) {
      int rbase = w * 32 + j * 16;
      stage16(Bb + (long)(bn + rbase + srow) * K + k0 + skc, Bs + rbase * 32);
    }
    __syncthreads();
    bf16x8 af[4], bfr[4];
#pragma unroll
    for (int t = 0; t < 4; ++t)
      af[t] = *(const bf16x8*)(As + (wm + t * 16 + (lane & 15)) * 32 + (lane >> 4) * 8);
#pragma unroll
    for (int t = 0; t < 4; ++t)
      bfr[t] = *(const bf16x8*)(Bs + (wn + t * 16 + (lane & 15)) * 32 + (lane >> 4) * 8);
#pragma unroll
    for (int mt = 0; mt < 4; ++mt)
#pragma unroll
      for (int nt = 0; nt < 4; ++nt)
        acc[mt][nt] = __builtin_amdgcn_mfma_f32_16x16x32_bf16(af[mt], bfr[nt], acc[mt][nt], 0, 0, 0);
    __syncthreads();
  }

  if constexpr (MODE != M_SSTAT) {
#pragma unroll
    for (int mt = 0; mt < 4; ++mt) {
#pragma unroll
      for (int nt = 0; nt < 4; ++nt) {
#pragma unroll
        for (int r = 0; r < 4; ++r) {
          int m = bmEff + wm + mt * 16 + (lane >> 4) * 4 + r;
          int n = bn + wn + nt * 16 + (lane & 15);
          float v = acc[mt][nt][r];
          if constexpr (MODE == M_CONV) {
            int g = m >> 8, mm = m & 255;
            const float* bias; __bf16* op; bool vlay;
            if (by < 8) {
              bias = (g == 0) ? bb0 : (g == 1) ? bb1 : (g == 2) ? bb2 : bb3;
              op   = (g == 0) ? o0  : (g == 1) ? o1  : (g == 2) ? o2  : o3;
              vlay = (g == 2);
            } else {
              bias = g ? bb5 : bb4;
              op   = g ? o5  : o4;
              vlay = (g == 1);
            }
            float vv = v + bias[mm];
            if (vlay) op[(long)z * sOz + (long)mm * HWSZ + n] = (__bf16)vv;   // V: [c,p]
            else      op[(long)z * sOz + (long)n * CCH + mm] = (__bf16)vv;    // Q/K: [p,c]
          } else if constexpr (MODE == M_G1) {
            int bz = z & 1, brr = z >> 1;
            const float* rs = brr ? bb4 : resid;
            float vv = v + bb0[m] + rs[(long)bz * sRz + (long)m * HWSZ + n];
            o0[(long)bz * sOz + (long)n * 512 + m + brr * 256] = (__bf16)vv;  // ZZ: [p, 512]
          } else if constexpr (MODE == M_FUSE) {
            fout[(long)z * sFz + (long)m * HWSZ + n] = v + bb0[m];
          }
        }
      }
    }
  }

  if constexpr (MODE == M_SSTAT) {
    // per-column (n=q) max / sumexp over this block's 128 rows (i)
    __shared__ float sm_[4][64], sl_[4][64];
#pragma unroll
    for (int nt = 0; nt < 4; ++nt) {
      float mx = -3.0e38f;
#pragma unroll
      for (int mt = 0; mt < 4; ++mt)
#pragma unroll
        for (int r = 0; r < 4; ++r) mx = fmaxf(mx, acc[mt][nt][r]);
      float sl = 0.f;
#pragma unroll
      for (int mt = 0; mt < 4; ++mt)
#pragma unroll
        for (int r = 0; r < 4; ++r) sl += exp2_fast((acc[mt][nt][r] - mx) * LOG2E);
#pragma unroll
      for (int d = 16; d <= 32; d <<= 1) {
        float om = __shfl_xor(mx, d, 64);
        float ol = __shfl_xor(sl, d, 64);
        float nm = fmaxf(mx, om);
        sl = sl * exp2_fast((mx - nm) * LOG2E) + ol * exp2_fast((om - nm) * LOG2E);
        mx = nm;
      }
      if (lane < 16) { sm_[w][nt * 16 + lane] = mx; sl_[w][nt * 16 + lane] = sl; }
    }
    __syncthreads();
    if (tid < 128) {
      int hf = tid >> 6, c = tid & 63;
      float m1 = sm_[hf][c],     l1 = sl_[hf][c];
      float m2 = sm_[hf + 2][c], l2 = sl_[hf + 2][c];
      float nm = fmaxf(m1, m2);
      float ll = l1 * exp2_fast((m1 - nm) * LOG2E) + l2 * exp2_fast((m2 - nm) * LOG2E);
      pmo[((long)z * 32 + by) * 4096 + bn + tid] = nm;
      plo[((long)z * 32 + by) * 4096 + bn + tid] = ll;
    }
  }
}

// ---------------------------------------------------------------------------
// Fused recompute-S attention PV:
// G[i,j] = sum_q exp(S[i,q]-m_q)*linv_q * V[j,q], S[i,q] = sum_c Qt[i,c] Kt[q,c]
// Block: i-tile 64, all j=256, one (z,br), one q-half (2048). fp32 partials.
// ---------------------------------------------------------------------------
__global__ __launch_bounds__(256)
void fused_pv(const __bf16* __restrict__ qs, const __bf16* __restrict__ qc,
              const __bf16* __restrict__ ks, const __bf16* __restrict__ kc,
              const __bf16* __restrict__ vs, const __bf16* __restrict__ vc,
              const float* __restrict__ mst, const float* __restrict__ lst,
              float* __restrict__ gacc)
{
  __shared__ __align__(16) __bf16 Qres[64 * 264];   // Q-tile resident, padded
  __shared__ __align__(16) __bf16 Pl[64 * 136];     // P transpose buffer, padded
  __shared__ __align__(16) __bf16 Kst[128 * 32];
  __shared__ __align__(16) __bf16 Vst[256 * 32];
  __shared__ float ms_[128], li_[128];

  const int tid = threadIdx.x, lane = tid & 63, w = tid >> 6;
  const int quad = lane >> 4, l15 = lane & 15;
  const int bi  = blockIdx.x * 64;
  const int zbr = blockIdx.y;           // br*2+z
  const int qh  = blockIdx.z;
  const int br = zbr >> 1, z = zbr & 1;
  const __bf16* Qt = (br ? qc : qs) + (long)z * 1048576;
  const __bf16* Kt = (br ? kc : ks) + (long)z * 1048576;
  const __bf16* Vv = (br ? vc : vs) + (long)z * 1048576;
  const float* msp = mst + (long)zbr * 4096;
  const float* lsp = lst + (long)zbr * 4096;
  float* go = gacc + ((long)qh * 4 + zbr) * 1048576;

  for (int idx = tid; idx < 2048; idx += 256) {
    int r = idx >> 5, c8 = (idx & 31) * 8;
    *(bf16x8*)(Qres + r * 264 + c8) = *(const bf16x8*)(Qt + (long)(bi + r) * 256 + c8);
  }

  f32x4 accO[4][4] = {};
  const int srow = lane >> 2, skc = (lane & 3) * 8;
  const int q0 = qh * 2048;

  for (int qc0 = q0; qc0 < q0 + 2048; qc0 += 128) {
    if (tid < 128) ms_[tid] = msp[qc0 + tid];
    else           li_[tid - 128] = lsp[qc0 + tid - 128];
    f32x4 accS[4][2] = {};
#pragma unroll
    for (int cs = 0; cs < 256; cs += 32) {
#pragma unroll
      for (int jj = 0; jj < 2; ++jj) {
        int rbase = w * 32 + jj * 16;
        stage16(Kt + (long)(qc0 + rbase + srow) * 256 + cs + skc, Kst + rbase * 32);
      }
      __syncthreads();
      bf16x8 aq[4], bk[2];
#pragma unroll
      for (int mt = 0; mt < 4; ++mt)
        aq[mt] = *(const bf16x8*)(Qres + (mt * 16 + l15) * 264 + cs + quad * 8);
#pragma unroll
      for (int nt = 0; nt < 2; ++nt)
        bk[nt] = *(const bf16x8*)(Kst + (w * 32 + nt * 16 + l15) * 32 + quad * 8);
#pragma unroll
      for (int mt = 0; mt < 4; ++mt)
#pragma unroll
        for (int nt = 0; nt < 2; ++nt)
          accS[mt][nt] = __builtin_amdgcn_mfma_f32_16x16x32_bf16(aq[mt], bk[nt], accS[mt][nt], 0, 0, 0);
      __syncthreads();
    }
    // P = exp(S - m_q)*linv_q -> LDS (transposed to [i][q])
#pragma unroll
    for (int mt = 0; mt < 4; ++mt)
#pragma unroll
      for (int nt = 0; nt < 2; ++nt) {
        int q = w * 32 + nt * 16 + l15;
        float mq = ms_[q], lq = li_[q];
#pragma unroll
        for (int r = 0; r < 4; ++r) {
          int i = mt * 16 + quad * 4 + r;
          Pl[i * 136 + q] = (__bf16)(exp2_fast((accS[mt][nt][r] - mq) * LOG2E) * lq);
        }
      }
    __syncthreads();
#pragma unroll
    for (int qs0 = 0; qs0 < 128; qs0 += 32) {
#pragma unroll
      for (int c = 0; c < 4; ++c) {
        int rbase = w * 64 + c * 16;
        stage16(Vv + (long)(rbase + srow) * 4096 + qc0 + qs0 + skc, Vst + rbase * 32);
      }
      __syncthreads();
      bf16x8 ap[4], bv[4];
#pragma unroll
      for (int mt = 0; mt < 4; ++mt)
        ap[mt] = *(const bf16x8*)(Pl + (mt * 16 + l15) * 136 + qs0 + quad * 8);
#pragma unroll
      for (int nt = 0; nt < 4; ++nt)
        bv[nt] = *(const bf16x8*)(Vst + (w * 64 + nt * 16 + l15) * 32 + quad * 8);
#pragma unroll
      for (int mt = 0; mt < 4; ++mt)
#pragma unroll
        for (int nt = 0; nt < 4; ++nt)
          accO[mt][nt] = __builtin_amdgcn_mfma_f32_16x16x32_bf16(ap[mt], bv[nt], accO[mt][nt], 0, 0, 0);
      __syncthreads();
    }
  }
  // scatter into raw-reshape layout (fp32 partial per q-half)
#pragma unroll
  for (int mt = 0; mt < 4; ++mt)
#pragma unroll
    for (int nt = 0; nt < 4; ++nt)
#pragma unroll
      for (int r = 0; r < 4; ++r) {
        int ig = bi + mt * 16 + quad * 4 + r;
        int j  = w * 64 + nt * 16 + l15;
        go[(long)((ig & 15) * 256 + j) * 256 + (ig >> 4)] = accO[mt][nt][r];
      }
}

// sum the two q-half partials -> bf16 GTS
__global__ void gsum(const float* __restrict__ ga, __bf16* __restrict__ gt) {
  long i = (long)blockIdx.x * 256 + threadIdx.x;   // over 1048576 f32x4 groups
  f32x4 a = *(const f32x4*)(ga + i * 4);
  f32x4 b = *(const f32x4*)(ga + 4194304 + i * 4);
  *(bf16x4*)(gt + i * 4) = __builtin_convertvector(a + b, bf16x4);
}

// ---------------------------------------------------------------------------
// Fl/Fv [b][256][4096] fp32  ->  Xt [img][4096][256] bf16 (img: Fl b0, Fl b1, Fv b0, Fv b1)
__global__ void transpose_cvt(const float* __restrict__ F0, const float* __restrict__ F1,
                              __bf16* __restrict__ Xt) {
  __shared__ float tile[32][33];
  int img = blockIdx.z;
  const float* src = (img < 2 ? F0 : F1) + (long)(img & 1) * (CCH * HWSZ);
  __bf16* dst = Xt + (long)img * (HWSZ * CCH);
  int p0 = blockIdx.x * 32, c0 = blockIdx.y * 32;
  int tx = threadIdx.x, ty = threadIdx.y;
#pragma unroll
  for (int j = 0; j < 32; j += 8)
    tile[ty + j][tx] = src[(long)(c0 + ty + j) * HWSZ + p0 + tx];
  __syncthreads();
#pragma unroll
  for (int j = 0; j < 32; j += 8)
    dst[(long)(p0 + ty + j) * CCH + c0 + tx] = (__bf16)tile[tx][ty + j];
}

// Xt [img][4096][256] -> im2col Cc [img][4096][2304], k = t*256+ci, zero-padded borders
__global__ void im2col_k(const __bf16* __restrict__ Xt, __bf16* __restrict__ Cc) {
  int img = blockIdx.y;
  int e = blockIdx.x * 256 + threadIdx.x;          // < 4096*288
  int p = e / 288;
  int c8 = e - p * 288;
  int t = c8 >> 5;                                 // 0..8
  int ci0 = (c8 & 31) * 8;
  int dy = t / 3 - 1, dx = t - (t / 3) * 3 - 1;
  int y = p >> 6, x = p & 63;
  int yy = y + dy, xx = x + dx;
  const __bf16* src = Xt + (long)img * (HWSZ * CCH);
  __bf16* dst = Cc + (long)img * 9437184 + (long)p * 2304 + t * 256 + ci0;
  uint4 v = make_uint4(0u, 0u, 0u, 0u);
  if ((unsigned)yy < 64u && (unsigned)xx < 64u)
    v = *(const uint4*)(src + (long)(yy * 64 + xx) * CCH + ci0);
  *(uint4*)dst = v;
}

// W[co][ci][3][3] fp32 -> A[co][t*256+ci] bf16, stacked: AL (Wqs,Wks,Wvs,Wqc), AV (Wkc,Wvc)
struct W6 { const float* w[6]; };
__global__ void repack_w3(W6 wp, __bf16* __restrict__ AL, __bf16* __restrict__ AV) {
  int zi = blockIdx.y;
  int e = blockIdx.x * 256 + threadIdx.x;          // < 256*2304
  int co = e / 2304;
  int rem = e - co * 2304;
  int t = rem >> 8, ci = rem & 255;
  float v = wp.w[zi][(long)co * 2304 + ci * 9 + t];
  __bf16* dst = (zi < 4) ? (AL + (long)zi * 256 * 2304) : (AV + (long)(zi - 4) * 256 * 2304);
  dst[(long)co * 2304 + rem] = (__bf16)v;
}

__global__ void cvt_bf(const float* __restrict__ s, __bf16* __restrict__ d, int n) {
  int i = blockIdx.x * 256 + threadIdx.x;
  if (i < n) d[i] = (__bf16)s[i];
}

// combine 32 row-chunk partial stats -> column max + 1/sumexp (per z)
__global__ void stats_combine(const float* __restrict__ pm, const float* __restrict__ pl,
                              float* __restrict__ mst, float* __restrict__ lst) {
  int q = blockIdx.x * 256 + threadIdx.x;
  int z = blockIdx.y;
  const float* pmz = pm + (long)z * 32 * 4096;
  const float* plz = pl + (long)z * 32 * 4096;
  float m = -3.0e38f;
#pragma unroll
  for (int rc = 0; rc < 32; ++rc) m = fmaxf(m, pmz[(long)rc * 4096 + q]);
  float l = 0.f;
#pragma unroll
  for (int rc = 0; rc < 32; ++rc)
    l += plz[(long)rc * 4096 + q] * exp2_fast((pmz[(long)rc * 4096 + q] - m) * LOG2E);
  mst[(long)z * 4096 + q] = m;
  lst[(long)z * 4096 + q] = 1.0f / l;
}

// ---------------------------------------------------------------------------
extern "C" void kernel_launch(void* const* d_in, const int* in_sizes, int n_in,
                              void* d_out, int out_size, void* d_ws, size_t ws_size,
                              hipStream_t stream) {
  const float* Fl  = (const float*)d_in[0];
  const float* Fv  = (const float*)d_in[1];
  const float* Wqs = (const float*)d_in[2];  const float* bqs = (const float*)d_in[3];
  const float* Wks = (const float*)d_in[4];  const float* bks = (const float*)d_in[5];
  const float* Wvs = (const float*)d_in[6];  const float* bvs = (const float*)d_in[7];
  const float* Wqc = (const float*)d_in[8];  const float* bqc = (const float*)d_in[9];
  const float* Wkc = (const float*)d_in[10]; const float* bkc = (const float*)d_in[11];
  const float* Wvc = (const float*)d_in[12]; const float* bvc = (const float*)d_in[13];
  const float* Wgs = (const float*)d_in[14]; const float* bgs = (const float*)d_in[15];
  const float* Wfu = (const float*)d_in[16]; const float* bfu = (const float*)d_in[17];

  char* ws = (char*)d_ws;
  size_t off = 0;
  auto take = [&](size_t bytes) -> void* {
    void* p = ws + off; off = (off + bytes + 255) & ~(size_t)255; return p;
  };
  __bf16* QST  = (__bf16*)take(4194304);   // Qs^T  [b][4096][256]
  __bf16* KST  = (__bf16*)take(4194304);
  __bf16* QCT  = (__bf16*)take(4194304);
  __bf16* KCT  = (__bf16*)take(4194304);
  __bf16* VS   = (__bf16*)take(4194304);   // Vs    [b][256][4096]
  __bf16* VC   = (__bf16*)take(4194304);
  __bf16* GTS  = (__bf16*)take(8388608);   // G (reshape layout) [br*2+z][4096][256]
  __bf16* ZZ   = (__bf16*)take(8388608);   // concat [b][4096][512]
  __bf16* AL   = (__bf16*)take(4718592);   // stacked conv weights [1024][2304]
  __bf16* AV   = (__bf16*)take(2359296);   // [512][2304]
  __bf16* WGSb = (__bf16*)take(131072);
  __bf16* WFSb = (__bf16*)take(262144);
  float*  MST  = (float*)take(65536);      // [br][z][4096]
  float*  LST  = (float*)take(65536);
  float*  PM   = (float*)take(1048576);    // [z][32][4096]
  float*  PL   = (float*)take(1048576);
  size_t ovl = off;                         // overlay region
  __bf16* Xt = (__bf16*)take(8388608);      // conv phase only
  __bf16* Cc = (__bf16*)take(75497472);     // conv phase only
  size_t needConv = off;
  float* GACC = (float*)(ws + ovl);         // attn phase: [2 qh][4 zbr][1M] fp32 = 32 MB
  size_t needAttn = ovl + 33554432;
  size_t need = needConv > needAttn ? needConv : needAttn;
  if (ws_size < need) return;               // fail cleanly instead of faulting

  const long Z1 = 1048576;                  // per-batch stride (elements)

  transpose_cvt<<<dim3(128, 8, 4), dim3(32, 8), 0, stream>>>(Fl, Fv, Xt);
  im2col_k<<<dim3(4608, 4), 256, 0, stream>>>(Xt, Cc);
  W6 wp; wp.w[0]=Wqs; wp.w[1]=Wks; wp.w[2]=Wvs; wp.w[3]=Wqc; wp.w[4]=Wkc; wp.w[5]=Wvc;
  repack_w3<<<dim3(2304, 6), 256, 0, stream>>>(wp, AL, AV);
  cvt_bf<<<256, 256, 0, stream>>>(Wgs, WGSb, 65536);
  cvt_bf<<<512, 256, 0, stream>>>(Wfu, WFSb, 131072);

  // merged conv3x3 GEMM: y<8 -> AL x Cc(Fl imgs), y>=8 -> AV x Cc(Fv imgs)
  gemm_bt<M_CONV><<<dim3(32, 12, 2), 256, 0, stream>>>(
      AL, 0, Cc, 9437184, 4096, 2304,
      QST, KST, VS, QCT, Z1,
      nullptr, 0,
      bqs, bks, bvs, bqc,
      nullptr, 0, nullptr, nullptr,
      KCT, VC, bkc, bvc, AV);

  for (int br = 0; br < 2; ++br) {
    const __bf16* Qt = br ? QCT : QST;
    const __bf16* Kt = br ? KCT : KST;
    // stats pass: S = Qt Kt^T, per-(i-chunk, q) partial max/sumexp (no store)
    gemm_bt<M_SSTAT><<<dim3(32, 32, 2), 256, 0, stream>>>(
        Qt, Z1, Kt, Z1, 4096, 256,
        nullptr, nullptr, nullptr, nullptr, 0,
        nullptr, 0,
        nullptr, nullptr, nullptr, nullptr,
        nullptr, 0, PM, PL,
        nullptr, nullptr, nullptr, nullptr, nullptr);
    stats_combine<<<dim3(16, 2), 256, 0, stream>>>(PM, PL, MST + br * 8192, LST + br * 8192);
  }
  // fused recompute-S PV for all (br, z, q-half)
  fused_pv<<<dim3(64, 4, 2), 256, 0, stream>>>(
      QST, QCT, KST, KCT, VS, VC, MST, LST, GACC);
  gsum<<<dim3(4096), 256, 0, stream>>>(GACC, GTS);

  // 1x1 conv + bias + residual -> ZZ (both branches in one dispatch)
  gemm_bt<M_G1><<<dim3(32, 2, 4), 256, 0, stream>>>(
      WGSb, 0, GTS, Z1, 4096, 256,
      ZZ, nullptr, nullptr, nullptr, (long)2097152,
      nullptr, 0,
      bgs, nullptr, nullptr, nullptr,
      Fl, Z1, nullptr, nullptr,
      nullptr, nullptr, Fv, nullptr, nullptr);
  // fuse conv 1x1 over 512 channels -> fp32 out
  gemm_bt<M_FUSE><<<dim3(32, 2, 2), 256, 0, stream>>>(
      WFSb, 0, ZZ, (long)2097152, 4096, 512,
      nullptr, nullptr, nullptr, nullptr, 0,
      (float*)d_out, Z1,
      bfu, nullptr, nullptr, nullptr,
      nullptr, 0, nullptr, nullptr,
      nullptr, nullptr, nullptr, nullptr, nullptr);
}

// Round 5
// 482.657 us; speedup vs baseline: 1.1828x; 1.1828x over previous
//
#include <hip/hip_runtime.h>

typedef __bf16 bf16x4 __attribute__((ext_vector_type(4)));
typedef __bf16 bf16x8 __attribute__((ext_vector_type(8)));
typedef float  f32x4  __attribute__((ext_vector_type(4)));

#define HWSZ 4096
#define CCH  256
#define LOG2E 1.44269504088896340736f

enum { M_SSTAT = 0, M_CONV = 1, M_G1 = 4, M_FUSE = 5 };

__device__ __forceinline__ float exp2_fast(float x) {
#if __has_builtin(__builtin_amdgcn_exp2f)
  return __builtin_amdgcn_exp2f(x);
#else
  return exp2f(x);
#endif
}

// stage 16B per lane into LDS; lane's data lands at lds_base + lane*16B
__device__ __forceinline__ void stage16(const __bf16* g, __bf16* ldsBase) {
#if __has_builtin(__builtin_amdgcn_global_load_lds)
  __builtin_amdgcn_global_load_lds(
      (const __attribute__((address_space(1))) void*)g,
      (__attribute__((address_space(3))) void*)ldsBase, 16, 0, 0);
#else
  int lane = threadIdx.x & 63;
  *(bf16x8*)(ldsBase + lane * 8) = *(const bf16x8*)g;
#endif
}

// ---------------------------------------------------------------------------
// Generic 128x128x32 bf16 MFMA GEMM, C = A * B^T, A[M,K], B[N,K] K-contiguous.
// 256 threads = 4 waves 2x2, wave 64x64 (4x4 16x16x32 MFMA tiles).
// M_CONV : merged conv3x3 GEMM. by<8: A=AL (M=1024, from Fl imgs), else A=A2=AV
//          (M=512, from Fv imgs). Outputs Q/K-type [p,c] or V-type [c,p].
// M_SSTAT: no C store; per-(128-row-chunk, column) softmax stats pm/pl only.
// M_G1   : 1x1 conv + bias + residual; blockIdx.z = br*2+z; writes concat ZZ.
// M_FUSE : 1x1 conv over 512ch + bias -> fp32 out.
// ---------------------------------------------------------------------------
template<int MODE>
__global__ __launch_bounds__(256)
void gemm_bt(const __bf16* __restrict__ A, long sAz,
             const __bf16* __restrict__ B, long sBz,
             int N, int K,
             __bf16* __restrict__ o0, __bf16* __restrict__ o1,
             __bf16* __restrict__ o2, __bf16* __restrict__ o3,
             long sOz,
             float* __restrict__ fout, long sFz,
             const float* __restrict__ bb0, const float* __restrict__ bb1,
             const float* __restrict__ bb2, const float* __restrict__ bb3,
             const float* __restrict__ resid, long sRz,
             float* __restrict__ pmo, float* __restrict__ plo,
             __bf16* __restrict__ o4, __bf16* __restrict__ o5,
             const float* __restrict__ bb4, const float* __restrict__ bb5,
             const __bf16* __restrict__ A2)
{
  __shared__ __align__(16) __bf16 smem[8192];
  __bf16* As = smem;
  __bf16* Bs = smem + 4096;

  const int tid  = threadIdx.x;
  const int lane = tid & 63;
  const int w    = tid >> 6;
  const int wm   = (w >> 1) * 64;
  const int wn   = (w & 1) * 64;
  const int z    = blockIdx.z;
  const int by   = blockIdx.y;
  const int bn   = blockIdx.x * 128;

  int bmEff = by * 128;
  const __bf16* Ab;
  const __bf16* Bb;
  if constexpr (MODE == M_CONV) {
    bool isL = (by < 8);
    bmEff = (isL ? by : by - 8) * 128;
    Ab = isL ? A : A2;
    Bb = B + (long)((isL ? 0 : 2) + z) * sBz;
  } else {
    Ab = A + (long)z * sAz;
    Bb = B + (long)z * sBz;
  }

  f32x4 acc[4][4] = {};

  const int srow = lane >> 2;       // row within 16-row staging chunk
  const int skc  = (lane & 3) * 8;  // k-element offset within row

  for (int k0 = 0; k0 < K; k0 += 32) {
#pragma unroll
    for (int j = 0; j < 2; ++j) {
      int rbase = w * 32 + j * 16;
      stage16(Ab + (long)(bmEff + rbase + srow) * K + k0 + skc, As + rbase * 32);
    }
#pragma unroll
    for (int j = 0; j < 2; ++j) {
      int rbase = w * 32 + j * 16;
      stage16(Bb + (long)(bn + rbase + srow) * K + k0 + skc, Bs + rbase * 32);
    }
    __syncthreads();
    bf16x8 af[4], bfr[4];
#pragma unroll
    for (int t = 0; t < 4; ++t)
      af[t] = *(const bf16x8*)(As + (wm + t * 16 + (lane & 15)) * 32 + (lane >> 4) * 8);
#pragma unroll
    for (int t = 0; t < 4; ++t)
      bfr[t] = *(const bf16x8*)(Bs + (wn + t * 16 + (lane & 15)) * 32 + (lane >> 4) * 8);
#pragma unroll
    for (int mt = 0; mt < 4; ++mt)
#pragma unroll
      for (int nt = 0; nt < 4; ++nt)
        acc[mt][nt] = __builtin_amdgcn_mfma_f32_16x16x32_bf16(af[mt], bfr[nt], acc[mt][nt], 0, 0, 0);
    __syncthreads();
  }

  if constexpr (MODE != M_SSTAT) {
#pragma unroll
    for (int mt = 0; mt < 4; ++mt) {
#pragma unroll
      for (int nt = 0; nt < 4; ++nt) {
#pragma unroll
        for (int r = 0; r < 4; ++r) {
          int m = bmEff + wm + mt * 16 + (lane >> 4) * 4 + r;
          int n = bn + wn + nt * 16 + (lane & 15);
          float v = acc[mt][nt][r];
          if constexpr (MODE == M_CONV) {
            int g = m >> 8, mm = m & 255;
            const float* bias; __bf16* op; bool vlay;
            if (by < 8) {
              bias = (g == 0) ? bb0 : (g == 1) ? bb1 : (g == 2) ? bb2 : bb3;
              op   = (g == 0) ? o0  : (g == 1) ? o1  : (g == 2) ? o2  : o3;
              vlay = (g == 2);
            } else {
              bias = g ? bb5 : bb4;
              op   = g ? o5  : o4;
              vlay = (g == 1);
            }
            float vv = v + bias[mm];
            if (vlay) op[(long)z * sOz + (long)mm * HWSZ + n] = (__bf16)vv;   // V: [c,p]
            else      op[(long)z * sOz + (long)n * CCH + mm] = (__bf16)vv;    // Q/K: [p,c]
          } else if constexpr (MODE == M_G1) {
            int bz = z & 1, brr = z >> 1;
            const float* rs = brr ? bb4 : resid;
            float vv = v + bb0[m] + rs[(long)bz * sRz + (long)m * HWSZ + n];
            o0[(long)bz * sOz + (long)n * 512 + m + brr * 256] = (__bf16)vv;  // ZZ: [p, 512]
          } else if constexpr (MODE == M_FUSE) {
            fout[(long)z * sFz + (long)m * HWSZ + n] = v + bb0[m];
          }
        }
      }
    }
  }

  if constexpr (MODE == M_SSTAT) {
    // per-column (n=q) max / sumexp over this block's 128 rows (i)
    __shared__ float sm_[4][64], sl_[4][64];
#pragma unroll
    for (int nt = 0; nt < 4; ++nt) {
      float mx = -3.0e38f;
#pragma unroll
      for (int mt = 0; mt < 4; ++mt)
#pragma unroll
        for (int r = 0; r < 4; ++r) mx = fmaxf(mx, acc[mt][nt][r]);
      float sl = 0.f;
#pragma unroll
      for (int mt = 0; mt < 4; ++mt)
#pragma unroll
        for (int r = 0; r < 4; ++r) sl += exp2_fast((acc[mt][nt][r] - mx) * LOG2E);
#pragma unroll
      for (int d = 16; d <= 32; d <<= 1) {
        float om = __shfl_xor(mx, d, 64);
        float ol = __shfl_xor(sl, d, 64);
        float nm = fmaxf(mx, om);
        sl = sl * exp2_fast((mx - nm) * LOG2E) + ol * exp2_fast((om - nm) * LOG2E);
        mx = nm;
      }
      if (lane < 16) { sm_[w][nt * 16 + lane] = mx; sl_[w][nt * 16 + lane] = sl; }
    }
    __syncthreads();
    if (tid < 128) {
      int hf = tid >> 6, c = tid & 63;
      float m1 = sm_[hf][c],     l1 = sl_[hf][c];
      float m2 = sm_[hf + 2][c], l2 = sl_[hf + 2][c];
      float nm = fmaxf(m1, m2);
      float ll = l1 * exp2_fast((m1 - nm) * LOG2E) + l2 * exp2_fast((m2 - nm) * LOG2E);
      pmo[((long)z * 32 + by) * 4096 + bn + tid] = nm;
      plo[((long)z * 32 + by) * 4096 + bn + tid] = ll;
    }
  }
}

// ---------------------------------------------------------------------------
// Fused recompute-S attention PV:
// G[i,j] = sum_q exp(S[i,q]-m_q)*linv_q * V[j,q], S[i,q] = sum_c Qt[i,c] Kt[q,c]
// Block: i-tile 64, all j=256, one (z,br), one q-half (2048).
// fp32 partials in NATURAL [i][j] layout (coalesced); reshape done in
// gsum_reshape (the round-4 scatter epilogue caused 255 MB RMW write traffic).
// ---------------------------------------------------------------------------
__global__ __launch_bounds__(256)
void fused_pv(const __bf16* __restrict__ qs, const __bf16* __restrict__ qc,
              const __bf16* __restrict__ ks, const __bf16* __restrict__ kc,
              const __bf16* __restrict__ vs, const __bf16* __restrict__ vc,
              const float* __restrict__ mst, const float* __restrict__ lst,
              float* __restrict__ gacc)
{
  __shared__ __align__(16) __bf16 Qres[64 * 260];   // pad 260: bank=2*row mod 32, 2-way free
  __shared__ __align__(16) __bf16 Pl[64 * 132];     // pad 132: same
  __shared__ __align__(16) __bf16 Kst[128 * 32];
  __shared__ __align__(16) __bf16 Vst[256 * 32];
  __shared__ float ms_[128], li_[128];

  const int tid = threadIdx.x, lane = tid & 63, w = tid >> 6;
  const int quad = lane >> 4, l15 = lane & 15;
  const int bi  = blockIdx.x * 64;
  const int zbr = blockIdx.y;           // br*2+z
  const int qh  = blockIdx.z;
  const int br = zbr >> 1, z = zbr & 1;
  const __bf16* Qt = (br ? qc : qs) + (long)z * 1048576;
  const __bf16* Kt = (br ? kc : ks) + (long)z * 1048576;
  const __bf16* Vv = (br ? vc : vs) + (long)z * 1048576;
  const float* msp = mst + (long)zbr * 4096;
  const float* lsp = lst + (long)zbr * 4096;
  float* go = gacc + ((long)qh * 4 + zbr) * 1048576;

  for (int idx = tid; idx < 2048; idx += 256) {
    int r = idx >> 5, c8 = (idx & 31) * 8;
    *(bf16x8*)(Qres + r * 260 + c8) = *(const bf16x8*)(Qt + (long)(bi + r) * 256 + c8);
  }

  f32x4 accO[4][4] = {};
  const int srow = lane >> 2, skc = (lane & 3) * 8;
  const int q0 = qh * 2048;

  for (int qc0 = q0; qc0 < q0 + 2048; qc0 += 128) {
    if (tid < 128) ms_[tid] = msp[qc0 + tid];
    else           li_[tid - 128] = lsp[qc0 + tid - 128];
    f32x4 accS[4][2] = {};
#pragma unroll
    for (int cs = 0; cs < 256; cs += 32) {
#pragma unroll
      for (int jj = 0; jj < 2; ++jj) {
        int rbase = w * 32 + jj * 16;
        stage16(Kt + (long)(qc0 + rbase + srow) * 256 + cs + skc, Kst + rbase * 32);
      }
      __syncthreads();
      bf16x8 aq[4], bk[2];
#pragma unroll
      for (int mt = 0; mt < 4; ++mt)
        aq[mt] = *(const bf16x8*)(Qres + (mt * 16 + l15) * 260 + cs + quad * 8);
#pragma unroll
      for (int nt = 0; nt < 2; ++nt)
        bk[nt] = *(const bf16x8*)(Kst + (w * 32 + nt * 16 + l15) * 32 + quad * 8);
#pragma unroll
      for (int mt = 0; mt < 4; ++mt)
#pragma unroll
        for (int nt = 0; nt < 2; ++nt)
          accS[mt][nt] = __builtin_amdgcn_mfma_f32_16x16x32_bf16(aq[mt], bk[nt], accS[mt][nt], 0, 0, 0);
      __syncthreads();
    }
    // P = exp(S - m_q)*linv_q -> LDS (transposed to [i][q])
#pragma unroll
    for (int mt = 0; mt < 4; ++mt)
#pragma unroll
      for (int nt = 0; nt < 2; ++nt) {
        int q = w * 32 + nt * 16 + l15;
        float mq = ms_[q], lq = li_[q];
#pragma unroll
        for (int r = 0; r < 4; ++r) {
          int i = mt * 16 + quad * 4 + r;
          Pl[i * 132 + q] = (__bf16)(exp2_fast((accS[mt][nt][r] - mq) * LOG2E) * lq);
        }
      }
    __syncthreads();
#pragma unroll
    for (int qs0 = 0; qs0 < 128; qs0 += 32) {
#pragma unroll
      for (int c = 0; c < 4; ++c) {
        int rbase = w * 64 + c * 16;
        stage16(Vv + (long)(rbase + srow) * 4096 + qc0 + qs0 + skc, Vst + rbase * 32);
      }
      __syncthreads();
      bf16x8 ap[4], bv[4];
#pragma unroll
      for (int mt = 0; mt < 4; ++mt)
        ap[mt] = *(const bf16x8*)(Pl + (mt * 16 + l15) * 132 + qs0 + quad * 8);
#pragma unroll
      for (int nt = 0; nt < 4; ++nt)
        bv[nt] = *(const bf16x8*)(Vst + (w * 64 + nt * 16 + l15) * 32 + quad * 8);
#pragma unroll
      for (int mt = 0; mt < 4; ++mt)
#pragma unroll
        for (int nt = 0; nt < 4; ++nt)
          accO[mt][nt] = __builtin_amdgcn_mfma_f32_16x16x32_bf16(ap[mt], bv[nt], accO[mt][nt], 0, 0, 0);
      __syncthreads();
    }
  }
  // natural-layout fp32 partial store (coalesced 64B segments)
#pragma unroll
  for (int mt = 0; mt < 4; ++mt)
#pragma unroll
    for (int nt = 0; nt < 4; ++nt)
#pragma unroll
      for (int r = 0; r < 4; ++r) {
        int i = mt * 16 + quad * 4 + r;
        int j = w * 64 + nt * 16 + l15;
        go[(long)(bi + i) * 256 + j] = accO[mt][nt][r];
      }
}

// ---------------------------------------------------------------------------
// Sum the two q-half partials (natural [i][j] fp32) and write GTS in the
// raw-reshape layout gt[p*256+ci], p=(i&15)*256+j, ci=i>>4 — via LDS
// transpose so every global read is a 256B run and every write a contiguous
// 32 KB block. grid (jg 4, v 16, zbr 4), 256 threads.
__global__ __launch_bounds__(256)
void gsum_reshape(const float* __restrict__ ga, __bf16* __restrict__ gt) {
  __shared__ __bf16 lds[64 * 260];
  const int t = threadIdx.x, lane = t & 63, w = t >> 6;
  const int zbr = blockIdx.z;
  const int v   = blockIdx.y;
  const int jg  = blockIdx.x;
  const float* g0 = ga + (long)zbr * 1048576;
  const float* g1 = g0 + 4194304;
  for (int ci0 = 0; ci0 < 256; ci0 += 4) {
    int ci = ci0 + w;
    long src = (long)(ci * 16 + v) * 256 + jg * 64 + lane;
    lds[lane * 260 + ci] = (__bf16)(g0[src] + g1[src]);
  }
  __syncthreads();
  __bf16* out = gt + (long)zbr * 1048576 + ((long)v * 256 + jg * 64) * 256;
#pragma unroll
  for (int pp = 0; pp < 8; ++pp) {
    int idx = pp * 256 + t;
    int row = idx >> 5, c8 = (idx & 31) * 8;
    *(bf16x8*)(out + (long)row * 256 + c8) = *(const bf16x8*)(lds + row * 260 + c8);
  }
}

// ---------------------------------------------------------------------------
// Fl/Fv [b][256][4096] fp32  ->  Xt [img][4096][256] bf16 (img: Fl b0, Fl b1, Fv b0, Fv b1)
__global__ void transpose_cvt(const float* __restrict__ F0, const float* __restrict__ F1,
                              __bf16* __restrict__ Xt) {
  __shared__ float tile[32][33];
  int img = blockIdx.z;
  const float* src = (img < 2 ? F0 : F1) + (long)(img & 1) * (CCH * HWSZ);
  __bf16* dst = Xt + (long)img * (HWSZ * CCH);
  int p0 = blockIdx.x * 32, c0 = blockIdx.y * 32;
  int tx = threadIdx.x, ty = threadIdx.y;
#pragma unroll
  for (int j = 0; j < 32; j += 8)
    tile[ty + j][tx] = src[(long)(c0 + ty + j) * HWSZ + p0 + tx];
  __syncthreads();
#pragma unroll
  for (int j = 0; j < 32; j += 8)
    dst[(long)(p0 + ty + j) * CCH + c0 + tx] = (__bf16)tile[tx][ty + j];
}

// Xt [img][4096][256] -> im2col Cc [img][4096][2304], k = t*256+ci, zero-padded borders
__global__ void im2col_k(const __bf16* __restrict__ Xt, __bf16* __restrict__ Cc) {
  int img = blockIdx.y;
  int e = blockIdx.x * 256 + threadIdx.x;          // < 4096*288
  int p = e / 288;
  int c8 = e - p * 288;
  int t = c8 >> 5;                                 // 0..8
  int ci0 = (c8 & 31) * 8;
  int dy = t / 3 - 1, dx = t - (t / 3) * 3 - 1;
  int y = p >> 6, x = p & 63;
  int yy = y + dy, xx = x + dx;
  const __bf16* src = Xt + (long)img * (HWSZ * CCH);
  __bf16* dst = Cc + (long)img * 9437184 + (long)p * 2304 + t * 256 + ci0;
  uint4 v = make_uint4(0u, 0u, 0u, 0u);
  if ((unsigned)yy < 64u && (unsigned)xx < 64u)
    v = *(const uint4*)(src + (long)(yy * 64 + xx) * CCH + ci0);
  *(uint4*)dst = v;
}

// W[co][ci][3][3] fp32 -> A[co][t*256+ci] bf16, stacked: AL (Wqs,Wks,Wvs,Wqc), AV (Wkc,Wvc)
struct W6 { const float* w[6]; };
__global__ void repack_w3(W6 wp, __bf16* __restrict__ AL, __bf16* __restrict__ AV) {
  int zi = blockIdx.y;
  int e = blockIdx.x * 256 + threadIdx.x;          // < 256*2304
  int co = e / 2304;
  int rem = e - co * 2304;
  int t = rem >> 8, ci = rem & 255;
  float v = wp.w[zi][(long)co * 2304 + ci * 9 + t];
  __bf16* dst = (zi < 4) ? (AL + (long)zi * 256 * 2304) : (AV + (long)(zi - 4) * 256 * 2304);
  dst[(long)co * 2304 + rem] = (__bf16)v;
}

__global__ void cvt_bf(const float* __restrict__ s, __bf16* __restrict__ d, int n) {
  int i = blockIdx.x * 256 + threadIdx.x;
  if (i < n) d[i] = (__bf16)s[i];
}

// combine 32 row-chunk partial stats -> column max + 1/sumexp (per z)
__global__ void stats_combine(const float* __restrict__ pm, const float* __restrict__ pl,
                              float* __restrict__ mst, float* __restrict__ lst) {
  int q = blockIdx.x * 256 + threadIdx.x;
  int z = blockIdx.y;
  const float* pmz = pm + (long)z * 32 * 4096;
  const float* plz = pl + (long)z * 32 * 4096;
  float m = -3.0e38f;
#pragma unroll
  for (int rc = 0; rc < 32; ++rc) m = fmaxf(m, pmz[(long)rc * 4096 + q]);
  float l = 0.f;
#pragma unroll
  for (int rc = 0; rc < 32; ++rc)
    l += plz[(long)rc * 4096 + q] * exp2_fast((pmz[(long)rc * 4096 + q] - m) * LOG2E);
  mst[(long)z * 4096 + q] = m;
  lst[(long)z * 4096 + q] = 1.0f / l;
}

// ---------------------------------------------------------------------------
extern "C" void kernel_launch(void* const* d_in, const int* in_sizes, int n_in,
                              void* d_out, int out_size, void* d_ws, size_t ws_size,
                              hipStream_t stream) {
  const float* Fl  = (const float*)d_in[0];
  const float* Fv  = (const float*)d_in[1];
  const float* Wqs = (const float*)d_in[2];  const float* bqs = (const float*)d_in[3];
  const float* Wks = (const float*)d_in[4];  const float* bks = (const float*)d_in[5];
  const float* Wvs = (const float*)d_in[6];  const float* bvs = (const float*)d_in[7];
  const float* Wqc = (const float*)d_in[8];  const float* bqc = (const float*)d_in[9];
  const float* Wkc = (const float*)d_in[10]; const float* bkc = (const float*)d_in[11];
  const float* Wvc = (const float*)d_in[12]; const float* bvc = (const float*)d_in[13];
  const float* Wgs = (const float*)d_in[14]; const float* bgs = (const float*)d_in[15];
  const float* Wfu = (const float*)d_in[16]; const float* bfu = (const float*)d_in[17];

  char* ws = (char*)d_ws;
  size_t off = 0;
  auto take = [&](size_t bytes) -> void* {
    void* p = ws + off; off = (off + bytes + 255) & ~(size_t)255; return p;
  };
  __bf16* QST  = (__bf16*)take(4194304);   // Qs^T  [b][4096][256]
  __bf16* KST  = (__bf16*)take(4194304);
  __bf16* QCT  = (__bf16*)take(4194304);
  __bf16* KCT  = (__bf16*)take(4194304);
  __bf16* VS   = (__bf16*)take(4194304);   // Vs    [b][256][4096]
  __bf16* VC   = (__bf16*)take(4194304);
  __bf16* GTS  = (__bf16*)take(8388608);   // G (reshape layout) [br*2+z][4096][256]
  __bf16* ZZ   = (__bf16*)take(8388608);   // concat [b][4096][512]
  __bf16* AL   = (__bf16*)take(4718592);   // stacked conv weights [1024][2304]
  __bf16* AV   = (__bf16*)take(2359296);   // [512][2304]
  __bf16* WGSb = (__bf16*)take(131072);
  __bf16* WFSb = (__bf16*)take(262144);
  float*  MST  = (float*)take(65536);      // [br][z][4096]
  float*  LST  = (float*)take(65536);
  float*  PM   = (float*)take(1048576);    // [z][32][4096]
  float*  PL   = (float*)take(1048576);
  size_t ovl = off;                         // overlay region
  __bf16* Xt = (__bf16*)take(8388608);      // conv phase only
  __bf16* Cc = (__bf16*)take(75497472);     // conv phase only
  size_t needConv = off;
  float* GACC = (float*)(ws + ovl);         // attn phase: [2 qh][4 zbr][4096*256] fp32 = 32 MB
  size_t needAttn = ovl + 33554432;
  size_t need = needConv > needAttn ? needConv : needAttn;
  if (ws_size < need) return;               // fail cleanly instead of faulting

  const long Z1 = 1048576;                  // per-batch stride (elements)

  transpose_cvt<<<dim3(128, 8, 4), dim3(32, 8), 0, stream>>>(Fl, Fv, Xt);
  im2col_k<<<dim3(4608, 4), 256, 0, stream>>>(Xt, Cc);
  W6 wp; wp.w[0]=Wqs; wp.w[1]=Wks; wp.w[2]=Wvs; wp.w[3]=Wqc; wp.w[4]=Wkc; wp.w[5]=Wvc;
  repack_w3<<<dim3(2304, 6), 256, 0, stream>>>(wp, AL, AV);
  cvt_bf<<<256, 256, 0, stream>>>(Wgs, WGSb, 65536);
  cvt_bf<<<512, 256, 0, stream>>>(Wfu, WFSb, 131072);

  // merged conv3x3 GEMM: y<8 -> AL x Cc(Fl imgs), y>=8 -> AV x Cc(Fv imgs)
  gemm_bt<M_CONV><<<dim3(32, 12, 2), 256, 0, stream>>>(
      AL, 0, Cc, 9437184, 4096, 2304,
      QST, KST, VS, QCT, Z1,
      nullptr, 0,
      bqs, bks, bvs, bqc,
      nullptr, 0, nullptr, nullptr,
      KCT, VC, bkc, bvc, AV);

  for (int br = 0; br < 2; ++br) {
    const __bf16* Qt = br ? QCT : QST;
    const __bf16* Kt = br ? KCT : KST;
    // stats pass: S = Qt Kt^T, per-(i-chunk, q) partial max/sumexp (no store)
    gemm_bt<M_SSTAT><<<dim3(32, 32, 2), 256, 0, stream>>>(
        Qt, Z1, Kt, Z1, 4096, 256,
        nullptr, nullptr, nullptr, nullptr, 0,
        nullptr, 0,
        nullptr, nullptr, nullptr, nullptr,
        nullptr, 0, PM, PL,
        nullptr, nullptr, nullptr, nullptr, nullptr);
    stats_combine<<<dim3(16, 2), 256, 0, stream>>>(PM, PL, MST + br * 8192, LST + br * 8192);
  }
  // fused recompute-S PV for all (br, z, q-half) -> natural-layout fp32 partials
  fused_pv<<<dim3(64, 4, 2), 256, 0, stream>>>(
      QST, QCT, KST, KCT, VS, VC, MST, LST, GACC);
  // sum partials + raw-reshape -> GTS (coalesced both sides)
  gsum_reshape<<<dim3(4, 16, 4), 256, 0, stream>>>(GACC, GTS);

  // 1x1 conv + bias + residual -> ZZ (both branches in one dispatch)
  gemm_bt<M_G1><<<dim3(32, 2, 4), 256, 0, stream>>>(
      WGSb, 0, GTS, Z1, 4096, 256,
      ZZ, nullptr, nullptr, nullptr, (long)2097152,
      nullptr, 0,
      bgs, nullptr, nullptr, nullptr,
      Fl, Z1, nullptr, nullptr,
      nullptr, nullptr, Fv, nullptr, nullptr);
  // fuse conv 1x1 over 512 channels -> fp32 out
  gemm_bt<M_FUSE><<<dim3(32, 2, 2), 256, 0, stream>>>(
      WFSb, 0, ZZ, (long)2097152, 4096, 512,
      nullptr, nullptr, nullptr, nullptr, 0,
      (float*)d_out, Z1,
      bfu, nullptr, nullptr, nullptr,
      nullptr, 0, nullptr, nullptr,
      nullptr, nullptr, nullptr, nullptr, nullptr);
}